// Round 3
// baseline (309.576 us; speedup 1.0000x reference)
//
#include <hip/hip_runtime.h>
#include <math.h>

#define BN 4096
#define FD 512
#define TILE 128
#define BK 32
#define NJB 32            // 128-wide j tiles
#define NPC 64            // partials per row: 32 tiles x 2 wave-stripes

typedef __attribute__((ext_vector_type(8))) __bf16 bf16x8;
typedef __attribute__((ext_vector_type(4))) float floatx4;

__device__ __forceinline__ float wred_sum(float v) {
#pragma unroll
  for (int m = 1; m < 64; m <<= 1) v += __shfl_xor(v, m, 64);
  return v;
}

__device__ __forceinline__ float dot4(float4 a, float4 b) {
  return a.x * b.x + a.y * b.y + a.z * b.z + a.w * b.w;
}

// round-to-nearest-even f32 -> bf16
__device__ __forceinline__ unsigned short f2bf(float x) {
  unsigned u = __float_as_uint(x);
  u += 0x7fffu + ((u >> 16) & 1u);
  return (unsigned short)(u >> 16);
}

__device__ __forceinline__ void load16(const void* g, void* l) {
  __builtin_amdgcn_global_load_lds(
      (const __attribute__((address_space(1))) unsigned int*)g,
      (__attribute__((address_space(3))) unsigned int*)l, 16, 0, 0);
}

// ------- Kernel 1: normalize rows -> bf16 g, recon partial -------
__global__ __launch_bounds__(64) void k_prep(const float* __restrict__ f,
                                             const float* __restrict__ fo,
                                             unsigned short* __restrict__ gb,
                                             float* __restrict__ acc) {
  const int i = blockIdx.x;
  const int lane = threadIdx.x;
  const float4* fr = (const float4*)(f + (size_t)i * FD);
  const float4* orr = (const float4*)(fo + (size_t)i * FD);
  float4 x0 = fr[lane], x1 = fr[lane + 64];
  float4 y0 = orr[lane], y1 = orr[lane + 64];
  float sff = dot4(x0, x0) + dot4(x1, x1);
  float sfo = dot4(x0, y0) + dot4(x1, y1);
  float soo = dot4(y0, y0) + dot4(y1, y1);
  sff = wred_sum(sff);
  sfo = wred_sum(sfo);
  soo = wred_sum(soo);
  float nf = sqrtf(sff);
  float inv = 1.0f / nf;
  ushort4* gr = (ushort4*)(gb + (size_t)i * FD);
  ushort4 s0, s1;
  s0.x = f2bf(x0.x * inv); s0.y = f2bf(x0.y * inv);
  s0.z = f2bf(x0.z * inv); s0.w = f2bf(x0.w * inv);
  s1.x = f2bf(x1.x * inv); s1.y = f2bf(x1.y * inv);
  s1.z = f2bf(x1.z * inv); s1.w = f2bf(x1.w * inv);
  gr[lane] = s0;
  gr[lane + 64] = s1;
  if (lane == 0) {
    float c = sfo / fmaxf(nf * sqrtf(soo), 1e-8f);
    atomicAdd(&acc[2], c);
  }
}

// ------- Kernel 2: bf16 MFMA g.gT; fused epilogue computes, per row-stripe:
//   sim argmax (diff label, adist<30), pos argmax (same label, max adist, j!=i),
//   neg-far argmin (diff label, min adist). -------
__global__ __launch_bounds__(256) void k_sim(const unsigned short* __restrict__ gb,
                                             const int* __restrict__ labels,
                                             const float* __restrict__ angles,
                                             float* __restrict__ pvalS,
                                             int* __restrict__ pidxS,
                                             float* __restrict__ pvalP,
                                             int* __restrict__ pidxP,
                                             float* __restrict__ pvalN,
                                             int* __restrict__ pidxN) {
  __shared__ unsigned short As[TILE * BK];   // row-major, 64B rows
  __shared__ unsigned short Bs[TILE * BK];
  const int tid = threadIdx.x;
  const int w = tid >> 6;
  const int lane = tid & 63;
  const int wi = w >> 1, wj = w & 1;
  const int i0 = blockIdx.y * TILE;
  const int j0 = blockIdx.x * TILE;

  floatx4 acc[4][4];
#pragma unroll
  for (int u = 0; u < 4; u++)
#pragma unroll
    for (int v = 0; v < 4; v++) acc[u][v] = (floatx4){0.f, 0.f, 0.f, 0.f};

  const int r1 = tid >> 2;          // rows 0..63
  const int q8 = (tid & 3) * 8;     // ushort offset of 16B chunk in row
  const unsigned short* gA1 = gb + (size_t)(i0 + r1) * FD + q8;
  const unsigned short* gA2 = gA1 + (size_t)64 * FD;
  const unsigned short* gB1 = gb + (size_t)(j0 + r1) * FD + q8;
  const unsigned short* gB2 = gB1 + (size_t)64 * FD;
  unsigned short* lA1 = As + tid * 8;
  unsigned short* lA2 = As + (tid + 256) * 8;
  unsigned short* lB1 = Bs + tid * 8;
  unsigned short* lB2 = Bs + (tid + 256) * 8;

  const int arow = wi * 64 + (lane & 15);   // + u*16
  const int brow = wj * 64 + (lane & 15);   // + v*16
  const int koff = (lane >> 4) * 8;         // k element offset in frag

  for (int kc = 0; kc < FD; kc += BK) {
    load16(gA1 + kc, lA1);
    load16(gA2 + kc, lA2);
    load16(gB1 + kc, lB1);
    load16(gB2 + kc, lB2);
    __syncthreads();
    bf16x8 a[4], b[4];
#pragma unroll
    for (int u = 0; u < 4; u++)
      a[u] = *(const bf16x8*)(As + (arow + u * 16) * BK + koff);
#pragma unroll
    for (int v = 0; v < 4; v++)
      b[v] = *(const bf16x8*)(Bs + (brow + v * 16) * BK + koff);
#pragma unroll
    for (int u = 0; u < 4; u++)
#pragma unroll
      for (int v = 0; v < 4; v++)
        acc[u][v] = __builtin_amdgcn_mfma_f32_16x16x32_bf16(a[u], b[v], acc[u][v], 0, 0, 0);
    __syncthreads();
  }

  // Epilogue: C layout col=lane&15, row=quad*4+reg (16x16 family).
  const int quad = lane >> 4;
  const int cx = lane & 15;
  int jc[4], lj[4];
  float aj[4][3];
#pragma unroll
  for (int v = 0; v < 4; v++) {
    jc[v] = j0 + wj * 64 + v * 16 + cx;
    lj[v] = labels[jc[v]];
    aj[v][0] = angles[jc[v] * 3 + 0];
    aj[v][1] = angles[jc[v] * 3 + 1];
    aj[v][2] = angles[jc[v] * 3 + 2];
  }
  const int pslot = blockIdx.x * 2 + wj;
#pragma unroll
  for (int u = 0; u < 4; u++) {
#pragma unroll
    for (int reg = 0; reg < 4; reg++) {
      int i = i0 + wi * 64 + u * 16 + quad * 4 + reg;
      int li = labels[i];
      float a0 = angles[i * 3 + 0];
      float a1 = angles[i * 3 + 1];
      float a2 = angles[i * 3 + 2];
      float sbest = -1e30f;
      int sidx = 0x7fffffff;
      float pbest = -1e30f;        // max dd, same label, j!=i
      int pidx = 0x7fffffff;
      float nbest = 1e30f;         // min dd, diff label
      int nidx = 0x7fffffff;
#pragma unroll
      for (int v = 0; v < 4; v++) {
        float d0 = a0 - aj[v][0];
        float d1 = a1 - aj[v][1];
        float d2 = a2 - aj[v][2];
        float dd = d0 * d0 + d1 * d1 + d2 * d2;
        float val = acc[u][v][reg];
        int j = jc[v];
        if (li == lj[v]) {
          if (j != i && dd > pbest) { pbest = dd; pidx = j; }
        } else {
          if (dd < nbest) { nbest = dd; nidx = j; }
          if (dd < 900.0f && val > sbest) { sbest = val; sidx = j; }
        }
      }
#pragma unroll
      for (int off = 1; off < 16; off <<= 1) {
        float ov = __shfl_xor(sbest, off, 16);
        int oi = __shfl_xor(sidx, off, 16);
        if (ov > sbest || (ov == sbest && oi < sidx)) { sbest = ov; sidx = oi; }
        ov = __shfl_xor(pbest, off, 16);
        oi = __shfl_xor(pidx, off, 16);
        if (ov > pbest || (ov == pbest && oi < pidx)) { pbest = ov; pidx = oi; }
        ov = __shfl_xor(nbest, off, 16);
        oi = __shfl_xor(nidx, off, 16);
        if (ov < nbest || (ov == nbest && oi < nidx)) { nbest = ov; nidx = oi; }
      }
      if (cx == 0) {
        size_t o = (size_t)i * NPC + pslot;
        pvalS[o] = sbest;
        pidxS[o] = sidx;
        pvalP[o] = pbest;
        pidxP[o] = pidx;
        pvalN[o] = nbest;
        pidxN[o] = nidx;
      }
    }
  }
}

// ------- Kernel 3: per-row finalize — pure partial reduction, no scan -------
__global__ __launch_bounds__(64) void k_final(const float* __restrict__ f,
                                              const float* __restrict__ angles,
                                              const float* __restrict__ pvalS,
                                              const int* __restrict__ pidxS,
                                              const float* __restrict__ pvalP,
                                              const int* __restrict__ pidxP,
                                              const float* __restrict__ pvalN,
                                              const int* __restrict__ pidxN,
                                              float* __restrict__ acc) {
  const int i = blockIdx.x;
  const int lane = threadIdx.x;
  const size_t o = (size_t)i * NPC + lane;

  float sv = pvalS[o];
  int si = pidxS[o];
  float pv = pvalP[o];
  int pi = pidxP[o];
  float nv = pvalN[o];
  int ni = pidxN[o];
#pragma unroll
  for (int off = 1; off < 64; off <<= 1) {
    float ov = __shfl_xor(sv, off, 64);
    int oi = __shfl_xor(si, off, 64);
    if (ov > sv || (ov == sv && oi < si)) { sv = ov; si = oi; }
    ov = __shfl_xor(pv, off, 64);
    oi = __shfl_xor(pi, off, 64);
    if (ov > pv || (ov == pv && oi < pi)) { pv = ov; pi = oi; }
    ov = __shfl_xor(nv, off, 64);
    oi = __shfl_xor(ni, off, 64);
    if (ov < nv || (ov == nv && oi < ni)) { nv = ov; ni = oi; }
  }
  bool hp = pv > -5e29f;     // any same-label (j!=i)
  bool hn = nv < 5e29f;      // any diff-label
  if (!(hp && hn)) return;   // row contributes nothing
  bool sim_any = sv > -5e29f;
  int neg = sim_any ? si : ni;
  int pos = pi;

  // triplet distances (reference adds 1e-6 to the per-element difference)
  const float4* fa = (const float4*)(f + (size_t)i * FD);
  const float4* fp = (const float4*)(f + (size_t)pos * FD);
  const float4* fn = (const float4*)(f + (size_t)neg * FD);
  float sp = 0.0f, sn = 0.0f;
#pragma unroll
  for (int t = 0; t < 2; t++) {
    float4 xa = fa[lane + t * 64];
    float4 xp = fp[lane + t * 64];
    float4 xn = fn[lane + t * 64];
    float dp;
    dp = xa.x - xp.x + 1e-6f; sp += dp * dp;
    dp = xa.y - xp.y + 1e-6f; sp += dp * dp;
    dp = xa.z - xp.z + 1e-6f; sp += dp * dp;
    dp = xa.w - xp.w + 1e-6f; sp += dp * dp;
    dp = xa.x - xn.x + 1e-6f; sn += dp * dp;
    dp = xa.y - xn.y + 1e-6f; sn += dp * dp;
    dp = xa.z - xn.z + 1e-6f; sn += dp * dp;
    dp = xa.w - xn.w + 1e-6f; sn += dp * dp;
  }
  sp = wred_sum(sp);
  sn = wred_sum(sn);

  if (lane == 0) {
    float a0 = angles[i * 3 + 0];
    float a1 = angles[i * 3 + 1];
    float a2 = angles[i * 3 + 2];
    float pos_d = sqrtf(sp);
    float neg_d = sqrtf(sn);
    float p0 = a0 - angles[pos * 3 + 0];
    float p1 = a1 - angles[pos * 3 + 1];
    float p2 = a2 - angles[pos * 3 + 2];
    float pa = sqrtf(p0 * p0 + p1 * p1 + p2 * p2);
    float n0 = a0 - angles[neg * 3 + 0];
    float n1 = a1 - angles[neg * 3 + 1];
    float n2 = a2 - angles[neg * 3 + 2];
    float na = sqrtf(n0 * n0 + n1 * n1 + n2 * n2);
    float w = (pa > 45.0f ? 2.0f : 1.0f) * (na < 15.0f ? 1.5f : 1.0f);
    float basic = fmaxf(pos_d - neg_d + 0.2f, 0.0f);
    atomicAdd(&acc[0], w * basic);
    atomicAdd(&acc[1], 1.0f);
  }
}

// ------- Kernel 4: scalar assembly -------
__global__ void k_out(const float* __restrict__ acc, float* __restrict__ out) {
  float cnt = fmaxf(acc[1], 1.0f);
  float tri = acc[0] / cnt;
  float recon = 1.0f - acc[2] / (float)BN;
  out[0] = tri + 0.1f * recon;
}

extern "C" void kernel_launch(void* const* d_in, const int* in_sizes, int n_in,
                              void* d_out, int out_size, void* d_ws, size_t ws_size,
                              hipStream_t stream) {
  const float* feat = (const float*)d_in[0];
  const int* labels = (const int*)d_in[1];
  const float* angles = (const float*)d_in[2];
  const float* forig = (const float*)d_in[3];
  float* out = (float*)d_out;

  char* ws = (char*)d_ws;
  unsigned short* gb = (unsigned short*)ws;                    // 4 MB bf16 normalized rows
  size_t off = (size_t)BN * FD * sizeof(unsigned short);
  float* pvalS = (float*)(ws + off); off += (size_t)BN * NPC * 4;
  int* pidxS = (int*)(ws + off);     off += (size_t)BN * NPC * 4;
  float* pvalP = (float*)(ws + off); off += (size_t)BN * NPC * 4;
  int* pidxP = (int*)(ws + off);     off += (size_t)BN * NPC * 4;
  float* pvalN = (float*)(ws + off); off += (size_t)BN * NPC * 4;
  int* pidxN = (int*)(ws + off);     off += (size_t)BN * NPC * 4;
  float* acc = (float*)(ws + off);

  hipMemsetAsync(acc, 0, 4 * sizeof(float), stream);
  k_prep<<<BN, 64, 0, stream>>>(feat, forig, gb, acc);
  dim3 gs(NJB, NJB);
  k_sim<<<gs, 256, 0, stream>>>(gb, labels, angles, pvalS, pidxS, pvalP, pidxP, pvalN, pidxN);
  k_final<<<BN, 64, 0, stream>>>(feat, angles, pvalS, pidxS, pvalP, pidxP, pvalN, pidxN, acc);
  k_out<<<1, 1, 0, stream>>>(acc, out);
}

// Round 4
// 155.353 us; speedup vs baseline: 1.9927x; 1.9927x over previous
//
#include <hip/hip_runtime.h>
#include <math.h>

#define BN 4096
#define FD 512
#define TILE 128
#define BK 32
#define NJB 32            // 128-wide j tiles
#define NPC 64            // partials per row: 32 tiles x 2 wave-stripes

typedef __attribute__((ext_vector_type(8))) __bf16 bf16x8;
typedef __attribute__((ext_vector_type(4))) float floatx4;

__device__ __forceinline__ float wred_sum(float v) {
#pragma unroll
  for (int m = 1; m < 64; m <<= 1) v += __shfl_xor(v, m, 64);
  return v;
}

__device__ __forceinline__ float dot4(float4 a, float4 b) {
  return a.x * b.x + a.y * b.y + a.z * b.z + a.w * b.w;
}

// round-to-nearest-even f32 -> bf16
__device__ __forceinline__ unsigned short f2bf(float x) {
  unsigned u = __float_as_uint(x);
  u += 0x7fffu + ((u >> 16) & 1u);
  return (unsigned short)(u >> 16);
}

__device__ __forceinline__ void load16(const void* g, void* l) {
  __builtin_amdgcn_global_load_lds(
      (const __attribute__((address_space(1))) unsigned int*)g,
      (__attribute__((address_space(3))) unsigned int*)l, 16, 0, 0);
}

// ------- Kernel 1: normalize rows -> bf16 g, per-row recon cosine -------
__global__ __launch_bounds__(64) void k_prep(const float* __restrict__ f,
                                             const float* __restrict__ fo,
                                             unsigned short* __restrict__ gb,
                                             float* __restrict__ rowr) {
  const int i = blockIdx.x;
  const int lane = threadIdx.x;
  const float4* fr = (const float4*)(f + (size_t)i * FD);
  const float4* orr = (const float4*)(fo + (size_t)i * FD);
  float4 x0 = fr[lane], x1 = fr[lane + 64];
  float4 y0 = orr[lane], y1 = orr[lane + 64];
  float sff = dot4(x0, x0) + dot4(x1, x1);
  float sfo = dot4(x0, y0) + dot4(x1, y1);
  float soo = dot4(y0, y0) + dot4(y1, y1);
  sff = wred_sum(sff);
  sfo = wred_sum(sfo);
  soo = wred_sum(soo);
  float nf = sqrtf(sff);
  float inv = 1.0f / nf;
  ushort4* gr = (ushort4*)(gb + (size_t)i * FD);
  ushort4 s0, s1;
  s0.x = f2bf(x0.x * inv); s0.y = f2bf(x0.y * inv);
  s0.z = f2bf(x0.z * inv); s0.w = f2bf(x0.w * inv);
  s1.x = f2bf(x1.x * inv); s1.y = f2bf(x1.y * inv);
  s1.z = f2bf(x1.z * inv); s1.w = f2bf(x1.w * inv);
  gr[lane] = s0;
  gr[lane + 64] = s1;
  if (lane == 0) {
    rowr[i] = sfo / fmaxf(nf * sqrtf(soo), 1e-8f);
  }
}

// ------- Kernel 2: bf16 MFMA g.gT; fused epilogue computes, per row-stripe:
//   sim argmax (diff label, adist<30), pos argmax (same label, max adist, j!=i),
//   neg-far argmin (diff label, min adist). -------
__global__ __launch_bounds__(256) void k_sim(const unsigned short* __restrict__ gb,
                                             const int* __restrict__ labels,
                                             const float* __restrict__ angles,
                                             float* __restrict__ pvalS,
                                             int* __restrict__ pidxS,
                                             float* __restrict__ pvalP,
                                             int* __restrict__ pidxP,
                                             float* __restrict__ pvalN,
                                             int* __restrict__ pidxN) {
  __shared__ unsigned short As[TILE * BK];   // row-major, 64B rows
  __shared__ unsigned short Bs[TILE * BK];
  const int tid = threadIdx.x;
  const int w = tid >> 6;
  const int lane = tid & 63;
  const int wi = w >> 1, wj = w & 1;
  const int i0 = blockIdx.y * TILE;
  const int j0 = blockIdx.x * TILE;

  floatx4 acc[4][4];
#pragma unroll
  for (int u = 0; u < 4; u++)
#pragma unroll
    for (int v = 0; v < 4; v++) acc[u][v] = (floatx4){0.f, 0.f, 0.f, 0.f};

  const int r1 = tid >> 2;          // rows 0..63
  const int q8 = (tid & 3) * 8;     // ushort offset of 16B chunk in row
  const unsigned short* gA1 = gb + (size_t)(i0 + r1) * FD + q8;
  const unsigned short* gA2 = gA1 + (size_t)64 * FD;
  const unsigned short* gB1 = gb + (size_t)(j0 + r1) * FD + q8;
  const unsigned short* gB2 = gB1 + (size_t)64 * FD;
  unsigned short* lA1 = As + tid * 8;
  unsigned short* lA2 = As + (tid + 256) * 8;
  unsigned short* lB1 = Bs + tid * 8;
  unsigned short* lB2 = Bs + (tid + 256) * 8;

  const int arow = wi * 64 + (lane & 15);   // + u*16
  const int brow = wj * 64 + (lane & 15);   // + v*16
  const int koff = (lane >> 4) * 8;         // k element offset in frag

  for (int kc = 0; kc < FD; kc += BK) {
    load16(gA1 + kc, lA1);
    load16(gA2 + kc, lA2);
    load16(gB1 + kc, lB1);
    load16(gB2 + kc, lB2);
    __syncthreads();
    bf16x8 a[4], b[4];
#pragma unroll
    for (int u = 0; u < 4; u++)
      a[u] = *(const bf16x8*)(As + (arow + u * 16) * BK + koff);
#pragma unroll
    for (int v = 0; v < 4; v++)
      b[v] = *(const bf16x8*)(Bs + (brow + v * 16) * BK + koff);
#pragma unroll
    for (int u = 0; u < 4; u++)
#pragma unroll
      for (int v = 0; v < 4; v++)
        acc[u][v] = __builtin_amdgcn_mfma_f32_16x16x32_bf16(a[u], b[v], acc[u][v], 0, 0, 0);
    __syncthreads();
  }

  // Epilogue: C layout col=lane&15, row=quad*4+reg (16x16 family).
  const int quad = lane >> 4;
  const int cx = lane & 15;
  int jc[4], lj[4];
  float aj[4][3];
#pragma unroll
  for (int v = 0; v < 4; v++) {
    jc[v] = j0 + wj * 64 + v * 16 + cx;
    lj[v] = labels[jc[v]];
    aj[v][0] = angles[jc[v] * 3 + 0];
    aj[v][1] = angles[jc[v] * 3 + 1];
    aj[v][2] = angles[jc[v] * 3 + 2];
  }
  const int pslot = blockIdx.x * 2 + wj;
#pragma unroll
  for (int u = 0; u < 4; u++) {
#pragma unroll
    for (int reg = 0; reg < 4; reg++) {
      int i = i0 + wi * 64 + u * 16 + quad * 4 + reg;
      int li = labels[i];
      float a0 = angles[i * 3 + 0];
      float a1 = angles[i * 3 + 1];
      float a2 = angles[i * 3 + 2];
      float sbest = -1e30f;
      int sidx = 0x7fffffff;
      float pbest = -1e30f;        // max dd, same label, j!=i
      int pidx = 0x7fffffff;
      float nbest = 1e30f;         // min dd, diff label
      int nidx = 0x7fffffff;
#pragma unroll
      for (int v = 0; v < 4; v++) {
        float d0 = a0 - aj[v][0];
        float d1 = a1 - aj[v][1];
        float d2 = a2 - aj[v][2];
        float dd = d0 * d0 + d1 * d1 + d2 * d2;
        float val = acc[u][v][reg];
        int j = jc[v];
        if (li == lj[v]) {
          if (j != i && dd > pbest) { pbest = dd; pidx = j; }
        } else {
          if (dd < nbest) { nbest = dd; nidx = j; }
          if (dd < 900.0f && val > sbest) { sbest = val; sidx = j; }
        }
      }
#pragma unroll
      for (int off = 1; off < 16; off <<= 1) {
        float ov = __shfl_xor(sbest, off, 16);
        int oi = __shfl_xor(sidx, off, 16);
        if (ov > sbest || (ov == sbest && oi < sidx)) { sbest = ov; sidx = oi; }
        ov = __shfl_xor(pbest, off, 16);
        oi = __shfl_xor(pidx, off, 16);
        if (ov > pbest || (ov == pbest && oi < pidx)) { pbest = ov; pidx = oi; }
        ov = __shfl_xor(nbest, off, 16);
        oi = __shfl_xor(nidx, off, 16);
        if (ov < nbest || (ov == nbest && oi < nidx)) { nbest = ov; nidx = oi; }
      }
      if (cx == 0) {
        size_t o = (size_t)i * NPC + pslot;
        pvalS[o] = sbest;
        pidxS[o] = sidx;
        pvalP[o] = pbest;
        pidxP[o] = pidx;
        pvalN[o] = nbest;
        pidxN[o] = nidx;
      }
    }
  }
}

// ------- Kernel 3: per-row finalize — partial reduce + per-row write, NO atomics -------
__global__ __launch_bounds__(64) void k_final(const float* __restrict__ f,
                                              const float* __restrict__ angles,
                                              const float* __restrict__ pvalS,
                                              const int* __restrict__ pidxS,
                                              const float* __restrict__ pvalP,
                                              const int* __restrict__ pidxP,
                                              const float* __restrict__ pvalN,
                                              const int* __restrict__ pidxN,
                                              float* __restrict__ rowc,
                                              float* __restrict__ rowv) {
  const int i = blockIdx.x;
  const int lane = threadIdx.x;
  const size_t o = (size_t)i * NPC + lane;

  float sv = pvalS[o];
  int si = pidxS[o];
  float pv = pvalP[o];
  int pi = pidxP[o];
  float nv = pvalN[o];
  int ni = pidxN[o];
#pragma unroll
  for (int off = 1; off < 64; off <<= 1) {
    float ov = __shfl_xor(sv, off, 64);
    int oi = __shfl_xor(si, off, 64);
    if (ov > sv || (ov == sv && oi < si)) { sv = ov; si = oi; }
    ov = __shfl_xor(pv, off, 64);
    oi = __shfl_xor(pi, off, 64);
    if (ov > pv || (ov == pv && oi < pi)) { pv = ov; pi = oi; }
    ov = __shfl_xor(nv, off, 64);
    oi = __shfl_xor(ni, off, 64);
    if (ov < nv || (ov == nv && oi < ni)) { nv = ov; ni = oi; }
  }
  bool hp = pv > -5e29f;     // any same-label (j!=i)
  bool hn = nv < 5e29f;      // any diff-label
  bool valid = hp && hn;
  if (!valid) {
    if (lane == 0) { rowc[i] = 0.0f; rowv[i] = 0.0f; }
    return;
  }
  bool sim_any = sv > -5e29f;
  int neg = sim_any ? si : ni;
  int pos = pi;

  // triplet distances (reference adds 1e-6 to the per-element difference)
  const float4* fa = (const float4*)(f + (size_t)i * FD);
  const float4* fp = (const float4*)(f + (size_t)pos * FD);
  const float4* fn = (const float4*)(f + (size_t)neg * FD);
  float sp = 0.0f, sn = 0.0f;
#pragma unroll
  for (int t = 0; t < 2; t++) {
    float4 xa = fa[lane + t * 64];
    float4 xp = fp[lane + t * 64];
    float4 xn = fn[lane + t * 64];
    float dp;
    dp = xa.x - xp.x + 1e-6f; sp += dp * dp;
    dp = xa.y - xp.y + 1e-6f; sp += dp * dp;
    dp = xa.z - xp.z + 1e-6f; sp += dp * dp;
    dp = xa.w - xp.w + 1e-6f; sp += dp * dp;
    dp = xa.x - xn.x + 1e-6f; sn += dp * dp;
    dp = xa.y - xn.y + 1e-6f; sn += dp * dp;
    dp = xa.z - xn.z + 1e-6f; sn += dp * dp;
    dp = xa.w - xn.w + 1e-6f; sn += dp * dp;
  }
  sp = wred_sum(sp);
  sn = wred_sum(sn);

  if (lane == 0) {
    float a0 = angles[i * 3 + 0];
    float a1 = angles[i * 3 + 1];
    float a2 = angles[i * 3 + 2];
    float pos_d = sqrtf(sp);
    float neg_d = sqrtf(sn);
    float p0 = a0 - angles[pos * 3 + 0];
    float p1 = a1 - angles[pos * 3 + 1];
    float p2 = a2 - angles[pos * 3 + 2];
    float pa = sqrtf(p0 * p0 + p1 * p1 + p2 * p2);
    float n0 = a0 - angles[neg * 3 + 0];
    float n1 = a1 - angles[neg * 3 + 1];
    float n2 = a2 - angles[neg * 3 + 2];
    float na = sqrtf(n0 * n0 + n1 * n1 + n2 * n2);
    float w = (pa > 45.0f ? 2.0f : 1.0f) * (na < 15.0f ? 1.5f : 1.0f);
    float basic = fmaxf(pos_d - neg_d + 0.2f, 0.0f);
    rowc[i] = w * basic;
    rowv[i] = 1.0f;
  }
}

// ------- Kernel 4: single-block tree reduction + scalar assembly -------
__global__ __launch_bounds__(1024) void k_out(const float* __restrict__ rowc,
                                              const float* __restrict__ rowv,
                                              const float* __restrict__ rowr,
                                              float* __restrict__ out) {
  __shared__ float sc[16], sv[16], sr[16];
  const int t = threadIdx.x;
  float c = 0.0f, v = 0.0f, r = 0.0f;
  for (int i = t; i < BN; i += 1024) {
    c += rowc[i];
    v += rowv[i];
    r += rowr[i];
  }
  c = wred_sum(c);
  v = wred_sum(v);
  r = wred_sum(r);
  const int wid = t >> 6;
  if ((t & 63) == 0) { sc[wid] = c; sv[wid] = v; sr[wid] = r; }
  __syncthreads();
  if (t == 0) {
    float C = 0.0f, V = 0.0f, R = 0.0f;
#pragma unroll
    for (int k = 0; k < 16; k++) { C += sc[k]; V += sv[k]; R += sr[k]; }
    float tri = C / fmaxf(V, 1.0f);
    float recon = 1.0f - R / (float)BN;
    out[0] = tri + 0.1f * recon;
  }
}

extern "C" void kernel_launch(void* const* d_in, const int* in_sizes, int n_in,
                              void* d_out, int out_size, void* d_ws, size_t ws_size,
                              hipStream_t stream) {
  const float* feat = (const float*)d_in[0];
  const int* labels = (const int*)d_in[1];
  const float* angles = (const float*)d_in[2];
  const float* forig = (const float*)d_in[3];
  float* out = (float*)d_out;

  char* ws = (char*)d_ws;
  unsigned short* gb = (unsigned short*)ws;                    // 4 MB bf16 normalized rows
  size_t off = (size_t)BN * FD * sizeof(unsigned short);
  float* pvalS = (float*)(ws + off); off += (size_t)BN * NPC * 4;
  int* pidxS = (int*)(ws + off);     off += (size_t)BN * NPC * 4;
  float* pvalP = (float*)(ws + off); off += (size_t)BN * NPC * 4;
  int* pidxP = (int*)(ws + off);     off += (size_t)BN * NPC * 4;
  float* pvalN = (float*)(ws + off); off += (size_t)BN * NPC * 4;
  int* pidxN = (int*)(ws + off);     off += (size_t)BN * NPC * 4;
  float* rowc = (float*)(ws + off);  off += (size_t)BN * 4;
  float* rowv = (float*)(ws + off);  off += (size_t)BN * 4;
  float* rowr = (float*)(ws + off);  off += (size_t)BN * 4;

  k_prep<<<BN, 64, 0, stream>>>(feat, forig, gb, rowr);
  dim3 gs(NJB, NJB);
  k_sim<<<gs, 256, 0, stream>>>(gb, labels, angles, pvalS, pidxS, pvalP, pidxP, pvalN, pidxN);
  k_final<<<BN, 64, 0, stream>>>(feat, angles, pvalS, pidxS, pvalP, pidxP, pvalN, pidxN, rowc, rowv);
  k_out<<<1, 1024, 0, stream>>>(rowc, rowv, rowr, out);
}